// Round 11
// baseline (196.621 us; speedup 1.0000x reference)
//
#include <hip/hip_runtime.h>
#include <hip/hip_bf16.h>

typedef __attribute__((ext_vector_type(8))) short short8;
typedef __attribute__((ext_vector_type(4))) float float4v;
typedef __attribute__((ext_vector_type(4))) short short4v;
typedef __attribute__((ext_vector_type(4))) unsigned int uint4v;
typedef __attribute__((ext_vector_type(2))) unsigned int uint2v;

#define B_ 2
#define S_ 2048
#define D_ 1024
#define H_ 16
#define HD_ 64
#define M_ 4096
#define LOG2E 1.442695040888963f

__device__ __forceinline__ unsigned short f2bf(float f) {
  unsigned int u = __builtin_bit_cast(unsigned int, f);
  u += 0x7fffu + ((u >> 16) & 1u);   // RNE (finite values only)
  return (unsigned short)(u >> 16);
}

// packed f32x2 -> bf16x2 (RNE), one v_cvt_pk_bf16_f32
__device__ __forceinline__ unsigned int pkbf(float a, float b) {
  __hip_bfloat162 h = __float22bfloat162_rn(make_float2(a, b));
  unsigned int u;
  __builtin_memcpy(&u, &h, sizeof(u));   // bit_cast rejects non-trivially-copyable
  return u;
}

__device__ __forceinline__ void gload_lds16(const void* g, void* l) {
  __builtin_amdgcn_global_load_lds(
      (const __attribute__((address_space(1))) void*)g,
      (__attribute__((address_space(3))) void*)l, 16, 0, 0);
}

// ---------------------------------------------------------------------------
// f32 -> bf16 cast: x (4 segs of 1M) + qw/kw/vw/ow (1M each) into d_ws.
// (byte-identical to round 9)
// ---------------------------------------------------------------------------
__global__ __launch_bounds__(256, 4) void cvt_kernel(
    const float* __restrict__ x,  const float* __restrict__ qw,
    const float* __restrict__ kw, const float* __restrict__ vw,
    const float* __restrict__ ow, unsigned short* __restrict__ dst)
{
  const int seg = blockIdx.y;
  const float* src;
  size_t doff;
  if (seg < 4)       { src = x + (size_t)seg * 1048576; doff = (size_t)seg * 1048576; }
  else if (seg == 4) { src = qw; doff = 4194304u; }
  else if (seg == 5) { src = kw; doff = 4194304u + 1048576u; }
  else if (seg == 6) { src = vw; doff = 4194304u + 2097152u; }
  else               { src = ow; doff = 4194304u + 3145728u; }
  const size_t i = ((size_t)blockIdx.x * 256 + threadIdx.x) * 4;
  float4v v = *(const float4v*)(src + i);
  short4v p;
#pragma unroll
  for (int r = 0; r < 4; ++r) p[r] = (short)f2bf(v[r]);
  *(short4v*)(dst + doff + i) = p;
}

// ---------------------------------------------------------------------------
// GEMM: out = X @ W^T + bias.  K-loop identical to round 9 (known good).
// mode 0: f32 [4096,1024]; mode 1: bf16 [B,H,S,hd] via LDS-transposed
// packed stores (NEW: was 64x 2B scalar stores/lane); mode 2: bf16 [B,H,hd,S].
// ---------------------------------------------------------------------------
__global__ __launch_bounds__(256, 2) void gemm_kernel(
    const unsigned short* __restrict__ X,
    const unsigned short* __restrict__ W0, const unsigned short* __restrict__ W1,
    const unsigned short* __restrict__ W2,
    const float* __restrict__ Bi0, const float* __restrict__ Bi1,
    const float* __restrict__ Bi2,
    unsigned short* O0, unsigned short* O1, unsigned short* O2,
    float* OutF, int md0, int md1, int md2)
{
  const int z = blockIdx.z;
  const unsigned short* W  = (z == 0) ? W0  : ((z == 1) ? W1  : W2);
  const float* Bi          = (z == 0) ? Bi0 : ((z == 1) ? Bi1 : Bi2);
  unsigned short* Out      = (z == 0) ? O0  : ((z == 1) ? O1  : O2);
  const int mode           = (z == 0) ? md0 : ((z == 1) ? md1 : md2);

  __shared__ __align__(16) char smem[128 * 32 * 2 * 2];
  __shared__ __align__(16) float tb[32 * 132];   // mode-1 transpose buffer
  char* As = smem;
  char* Bs = smem + 128 * 32 * 2;

  const int t = threadIdx.x, l = t & 63;
  const int w = t >> 6, lr = l & 15, lg = l >> 4;
  const int n0 = blockIdx.x * 128, m0 = blockIdx.y * 128;
  const int wm = (w >> 1) * 64, wn = (w & 1) * 64;

  float4v acc[4][4];
#pragma unroll
  for (int i = 0; i < 4; ++i)
#pragma unroll
    for (int j = 0; j < 4; ++j) acc[i][j] = (float4v){0.f, 0.f, 0.f, 0.f};

  const int c0 = t, c1 = t + 256;
  const int r0 = c0 >> 2, k80 = (c0 & 3) * 8;
  const int r1 = c1 >> 2, k81 = (c1 & 3) * 8;

  for (int k0 = 0; k0 < 1024; k0 += 32) {
    __syncthreads();
    gload_lds16(X + (size_t)(m0 + r0) * 1024 + k0 + k80, As + c0 * 16);
    gload_lds16(X + (size_t)(m0 + r1) * 1024 + k0 + k81, As + c1 * 16);
    gload_lds16(W + (size_t)(n0 + r0) * 1024 + k0 + k80, Bs + c0 * 16);
    gload_lds16(W + (size_t)(n0 + r1) * 1024 + k0 + k81, Bs + c1 * 16);
    __syncthreads();

    short8 af[4], bfr[4];
#pragma unroll
    for (int i = 0; i < 4; ++i)
      af[i] = *(const short8*)(As + (wm + i * 16 + lr) * 64 + lg * 16);
#pragma unroll
    for (int j = 0; j < 4; ++j)
      bfr[j] = *(const short8*)(Bs + (wn + j * 16 + lr) * 64 + lg * 16);
#pragma unroll
    for (int i = 0; i < 4; ++i)
#pragma unroll
      for (int j = 0; j < 4; ++j)
        acc[i][j] = __builtin_amdgcn_mfma_f32_16x16x32_bf16(af[i], bfr[j], acc[i][j], 0, 0, 0);
  }

  float bv[4];
#pragma unroll
  for (int j = 0; j < 4; ++j) bv[j] = Bi[n0 + wn + j * 16 + lr];

  if (mode == 1) {
    // LDS transpose epilogue: per i-block, stage 32x128 f32 (stride 132),
    // then each thread stores 16 contiguous bf16 (2x 16B stores).
    const int rbase = (w >> 1) * 16;
    const int row16 = t >> 3, chunk = t & 7;
#pragma unroll
    for (int i = 0; i < 4; ++i) {
#pragma unroll
      for (int j = 0; j < 4; ++j)
#pragma unroll
        for (int r = 0; r < 4; ++r)
          tb[(rbase + lg * 4 + r) * 132 + wn + j * 16 + lr] = acc[i][j][r] + bv[j];
      __syncthreads();
      const int grow = m0 + ((row16 < 16) ? (i * 16 + row16) : (64 + i * 16 + row16 - 16));
      const int b = grow >> 11, sl = grow & 2047;
      const int colg = n0 + chunk * 16;
      const int hh = colg >> 6, d0 = colg & 63;
      float4v v4[4];
#pragma unroll
      for (int q = 0; q < 4; ++q)
        v4[q] = *(const float4v*)(tb + row16 * 132 + chunk * 16 + q * 4);
      uint4v lo, hi;
#pragma unroll
      for (int q = 0; q < 2; ++q) {
        lo[q * 2]     = pkbf(v4[q][0], v4[q][1]);
        lo[q * 2 + 1] = pkbf(v4[q][2], v4[q][3]);
        hi[q * 2]     = pkbf(v4[q + 2][0], v4[q + 2][1]);
        hi[q * 2 + 1] = pkbf(v4[q + 2][2], v4[q + 2][3]);
      }
      unsigned short* dst = Out + ((size_t)(b * H_ + hh) * S_ + sl) * HD_ + d0;
      *(short8*)dst = __builtin_bit_cast(short8, lo);
      *(short8*)(dst + 8) = __builtin_bit_cast(short8, hi);
      __syncthreads();
    }
  } else {
#pragma unroll
    for (int i = 0; i < 4; ++i) {
      const int rowb = m0 + wm + i * 16 + lg * 4;
#pragma unroll
      for (int j = 0; j < 4; ++j) {
        const int col = n0 + wn + j * 16 + lr;
        if (mode == 2) {
          const int b = rowb >> 11, s = rowb & 2047;
          const int hh = col >> 6, d = col & 63;
          uint2v pk2;
          pk2[0] = pkbf(acc[i][j][0] + bv[j], acc[i][j][1] + bv[j]);
          pk2[1] = pkbf(acc[i][j][2] + bv[j], acc[i][j][3] + bv[j]);
          *(short4v*)(Out + ((size_t)(b * H_ + hh) * HD_ + d) * S_ + s) =
              __builtin_bit_cast(short4v, pk2);
        } else {
#pragma unroll
          for (int r = 0; r < 4; ++r)
            OutF[(size_t)(rowb + r) * 1024 + col] = acc[i][j][r] + bv[j];
        }
      }
    }
  }
}

// ---------------------------------------------------------------------------
// Flash attention v4 (round-9 verified structure); ONLY change: packed
// v_cvt_pk_bf16_f32 for P^T packing and the epilogue (same RNE math).
// ---------------------------------------------------------------------------
__global__ __launch_bounds__(256, 2) void attn_kernel(
    const unsigned short* __restrict__ Q, const unsigned short* __restrict__ K,
    const unsigned short* __restrict__ VT, unsigned short* __restrict__ O)
{
  // K dbuf 2x8KB + V dbuf 2x8KB + per-wave transpose buf 4x4416B
  __shared__ __align__(16) char smem[32768 + 4 * 4416];

  const int t = threadIdx.x, l = t & 63;
  const int w = t >> 6, lr = l & 15, lg = l >> 4;
  const int bh = blockIdx.x;
  const int it = 31 - (int)blockIdx.y;   // LPT: heavy tiles first
  const int h = bh & 15;

  const unsigned short* qbp = Q + (size_t)bh * S_ * HD_;
  const unsigned short* kbp = K + (size_t)bh * S_ * HD_;
  const unsigned short* vbp = VT + (size_t)bh * HD_ * S_;

  const float slope2 = __builtin_amdgcn_exp2f(-0.5f * (float)(h + 1)) * LOG2E;
  const float qksc = 0.125f * LOG2E;

  char* tw = smem + 32768 + w * 4416;  // wave-private transpose buffer

  // staging chunk mapping (XOR swizzle) -- identical to round 9
  const int g0 = t, g1 = t + 256;
  const int sr0 = g0 >> 3, sc0 = (g0 & 7) ^ (sr0 & 7);
  const int sr1 = g1 >> 3, sc1 = (g1 & 7) ^ (sr1 & 7);

  const int fchunk = ((4 + lg) ^ (lr & 7)) * 16;   // ks=1
  const int fchunk0 = ((lg) ^ (lr & 7)) * 16;      // ks=0

  const int qrow = it * 64 + w * 16;
  const int qpos = qrow + lr;

  float kb16[4][4];
#pragma unroll
  for (int nj = 0; nj < 4; ++nj)
#pragma unroll
    for (int r = 0; r < 4; ++r)
      kb16[nj][r] = slope2 * (float)(nj * 16 + lg * 4 + r);

  short8 qf[2];
#pragma unroll
  for (int ks = 0; ks < 2; ++ks)
    qf[ks] = *(const short8*)(qbp + (size_t)(qrow + lr) * HD_ + ks * 32 + lg * 8);

  float4v o_acc[4];
#pragma unroll
  for (int dt = 0; dt < 4; ++dt) o_acc[dt] = (float4v){0.f, 0.f, 0.f, 0.f};
  float m_st = -1e30f, l_st = 0.f;

  // prefetch j=0 into buffer 0
  gload_lds16(kbp + (size_t)sr0 * HD_ + sc0 * 8, smem + g0 * 16);
  gload_lds16(kbp + (size_t)sr1 * HD_ + sc1 * 8, smem + g1 * 16);
  gload_lds16(vbp + (size_t)sr0 * S_ + sc0 * 8, smem + 16384 + g0 * 16);
  gload_lds16(vbp + (size_t)sr1 * S_ + sc1 * 8, smem + 16384 + g1 * 16);
  __syncthreads();

  for (int j = 0; j <= it; ++j) {
    const int cur = j & 1;
    char* Ks = smem + (cur ? 8192 : 0);
    char* Vs = smem + 16384 + (cur ? 8192 : 0);
    if (j < it) {
      char* Kn = smem + (cur ? 0 : 8192);
      char* Vn = smem + 16384 + (cur ? 0 : 8192);
      const int jn = j + 1;
      gload_lds16(kbp + (size_t)(jn * 64 + sr0) * HD_ + sc0 * 8, Kn + g0 * 16);
      gload_lds16(kbp + (size_t)(jn * 64 + sr1) * HD_ + sc1 * 8, Kn + g1 * 16);
      gload_lds16(vbp + (size_t)sr0 * S_ + jn * 64 + sc0 * 8, Vn + g0 * 16);
      gload_lds16(vbp + (size_t)sr1 * S_ + jn * 64 + sc1 * 8, Vn + g1 * 16);
    }

    // S^T = K Q^T
    float4v s_acc[4];
#pragma unroll
    for (int nj = 0; nj < 4; ++nj) {
      s_acc[nj] = (float4v){0.f, 0.f, 0.f, 0.f};
      short8 kf0 = *(const short8*)(Ks + (nj * 16 + lr) * 128 + fchunk0);
      s_acc[nj] = __builtin_amdgcn_mfma_f32_16x16x32_bf16(kf0, qf[0], s_acc[nj], 0, 0, 0);
      short8 kf1 = *(const short8*)(Ks + (nj * 16 + lr) * 128 + fchunk);
      s_acc[nj] = __builtin_amdgcn_mfma_f32_16x16x32_bf16(kf1, qf[1], s_acc[nj], 0, 0, 0);
    }

    const float cj = slope2 * (float)(j * 64);
#pragma unroll
    for (int nj = 0; nj < 4; ++nj)
#pragma unroll
      for (int r = 0; r < 4; ++r)
        s_acc[nj][r] = s_acc[nj][r] * qksc + (cj + kb16[nj][r]);
    if (j == it) {
#pragma unroll
      for (int nj = 0; nj < 4; ++nj)
#pragma unroll
        for (int r = 0; r < 4; ++r) {
          const int kpos = j * 64 + nj * 16 + lg * 4 + r;
          if (kpos > qpos) s_acc[nj][r] = -1e30f;
        }
    }

    // online softmax: in-lane reduce over 16 + 2 cross-quad shuffles
    float mx = s_acc[0][0];
#pragma unroll
    for (int nj = 0; nj < 4; ++nj)
#pragma unroll
      for (int r = 0; r < 4; ++r) mx = fmaxf(mx, s_acc[nj][r]);
    mx = fmaxf(mx, __shfl_xor(mx, 16, 64));
    mx = fmaxf(mx, __shfl_xor(mx, 32, 64));
    const float mn = fmaxf(m_st, mx);
    const float alpha = __builtin_amdgcn_exp2f(m_st - mn);
    m_st = mn;
    float rsum = 0.f;
#pragma unroll
    for (int nj = 0; nj < 4; ++nj)
#pragma unroll
      for (int r = 0; r < 4; ++r) {
        const float p = __builtin_amdgcn_exp2f(s_acc[nj][r] - mn);
        s_acc[nj][r] = p;
        rsum += p;
      }
    rsum += __shfl_xor(rsum, 16, 64);
    rsum += __shfl_xor(rsum, 32, 64);
    l_st = alpha * l_st + rsum;
#pragma unroll
    for (int dt = 0; dt < 4; ++dt)
#pragma unroll
      for (int r = 0; r < 4; ++r) o_acc[dt][r] *= alpha;

    // P^T -> bf16 K=32 B-fragments via packed cvt (same RNE as before)
    short8 pT[2];
#pragma unroll
    for (int njp = 0; njp < 2; ++njp) {
      uint4v u;
      u[0] = pkbf(s_acc[njp * 2][0], s_acc[njp * 2][1]);
      u[1] = pkbf(s_acc[njp * 2][2], s_acc[njp * 2][3]);
      u[2] = pkbf(s_acc[njp * 2 + 1][0], s_acc[njp * 2 + 1][1]);
      u[3] = pkbf(s_acc[njp * 2 + 1][2], s_acc[njp * 2 + 1][3]);
      pT[njp] = __builtin_bit_cast(short8, u);
    }

    // O^T += V^T P^T
    const int vcl = lr & 7;
#pragma unroll
    for (int dt = 0; dt < 4; ++dt) {
      const char* rowp = Vs + (dt * 16 + lr) * 128;
#pragma unroll
      for (int njp = 0; njp < 2; ++njp) {
        const int cA = ((njp * 4 + (lg >> 1)) ^ vcl) * 16 + (lg & 1) * 8;
        const int cB = ((njp * 4 + 2 + (lg >> 1)) ^ vcl) * 16 + (lg & 1) * 8;
        short4v v0 = *(const short4v*)(rowp + cA);
        short4v v1 = *(const short4v*)(rowp + cB);
        short8 vf8;
#pragma unroll
        for (int e = 0; e < 4; ++e) { vf8[e] = v0[e]; vf8[e + 4] = v1[e]; }
        o_acc[dt] = __builtin_amdgcn_mfma_f32_16x16x32_bf16(vf8, pT[njp], o_acc[dt], 0, 0, 0);
      }
    }
    __syncthreads();
  }

  // epilogue: un-transpose O^T via wave-private LDS, coalesced bf16 store
#pragma unroll
  for (int dt = 0; dt < 4; ++dt)
#pragma unroll
    for (int r = 0; r < 4; ++r)
      *(float*)(tw + ((dt * 16 + lg * 4 + r) * 17 + lr) * 4) = o_acc[dt][r];
  if (lg == 0) *(float*)(tw + 4352 + lr * 4) = l_st;

  const int q2 = l >> 2, dbase = (l & 3) * 16;
  const float invl = 1.0f / *(const float*)(tw + 4352 + q2 * 4);
  uint4v os0, os1;
#pragma unroll
  for (int k = 0; k < 8; ++k) {
    const float va = *(const float*)(tw + ((dbase + 2 * k) * 17 + q2) * 4) * invl;
    const float vb = *(const float*)(tw + ((dbase + 2 * k + 1) * 17 + q2) * 4) * invl;
    if (k < 4) os0[k] = pkbf(va, vb); else os1[k - 4] = pkbf(va, vb);
  }
  const int brow = (bh >> 4) * S_;
  unsigned short* op = O + (size_t)(brow + qrow + q2) * 1024 + h * 64 + dbase;
  *(short8*)op = __builtin_bit_cast(short8, os0);
  *(short8*)(op + 8) = __builtin_bit_cast(short8, os1);
}

extern "C" void kernel_launch(void* const* d_in, const int* in_sizes, int n_in,
                              void* d_out, int out_size, void* d_ws, size_t ws_size,
                              hipStream_t stream) {
  (void)in_sizes; (void)n_in; (void)out_size; (void)ws_size;
  const float* x  = (const float*)d_in[0];
  const float* qw = (const float*)d_in[1];
  const float* qb = (const float*)d_in[2];
  const float* kw = (const float*)d_in[3];
  const float* kb = (const float*)d_in[4];
  const float* vw = (const float*)d_in[5];
  const float* vb = (const float*)d_in[6];
  const float* ow = (const float*)d_in[7];
  const float* ob = (const float*)d_in[8];
  float* out = (float*)d_out;

  unsigned short* xb  = (unsigned short*)d_ws;              // [4096,1024] bf16
  unsigned short* qwb = xb  + (size_t)M_ * D_;
  unsigned short* kwb = qwb + (size_t)D_ * D_;
  unsigned short* vwb = kwb + (size_t)D_ * D_;
  unsigned short* owb = vwb + (size_t)D_ * D_;
  unsigned short* qws = owb + (size_t)D_ * D_;              // [B,H,S,hd]
  unsigned short* kws = qws + (size_t)M_ * D_;              // [B,H,S,hd]
  unsigned short* vws = kws + (size_t)M_ * D_;              // [B,H,hd,S]
  unsigned short* aws = vws + (size_t)M_ * D_;              // [B*S, H*hd]

  cvt_kernel<<<dim3(1024, 8), dim3(256), 0, stream>>>(x, qw, kw, vw, ow, xb);
  gemm_kernel<<<dim3(8, 32, 3), dim3(256), 0, stream>>>(
      xb, qwb, kwb, vwb, qb, kb, vb, qws, kws, vws, out, 1, 1, 2);
  attn_kernel<<<dim3(32, 32), dim3(256), 0, stream>>>(qws, kws, vws, aws);
  gemm_kernel<<<dim3(8, 32, 1), dim3(256), 0, stream>>>(
      aws, owb, owb, owb, ob, ob, ob, aws, aws, aws, out, 0, 0, 0);
}

// Round 12
// 194.399 us; speedup vs baseline: 1.0114x; 1.0114x over previous
//
#include <hip/hip_runtime.h>
#include <hip/hip_bf16.h>

typedef __attribute__((ext_vector_type(8))) short short8;
typedef __attribute__((ext_vector_type(4))) float float4v;
typedef __attribute__((ext_vector_type(4))) short short4v;
typedef __attribute__((ext_vector_type(4))) unsigned int uint4v;
typedef __attribute__((ext_vector_type(2))) unsigned int uint2v;

#define B_ 2
#define S_ 2048
#define D_ 1024
#define H_ 16
#define HD_ 64
#define M_ 4096
#define LOG2E 1.442695040888963f

__device__ __forceinline__ unsigned short f2bf(float f) {
  unsigned int u = __builtin_bit_cast(unsigned int, f);
  u += 0x7fffu + ((u >> 16) & 1u);   // RNE (finite values only)
  return (unsigned short)(u >> 16);
}

// packed f32x2 -> bf16x2 (RNE), one v_cvt_pk_bf16_f32
__device__ __forceinline__ unsigned int pkbf(float a, float b) {
  __hip_bfloat162 h = __float22bfloat162_rn(make_float2(a, b));
  unsigned int u;
  __builtin_memcpy(&u, &h, sizeof(u));   // bit_cast rejects non-trivially-copyable
  return u;
}

__device__ __forceinline__ void gload_lds16(const void* g, void* l) {
  __builtin_amdgcn_global_load_lds(
      (const __attribute__((address_space(1))) void*)g,
      (__attribute__((address_space(3))) void*)l, 16, 0, 0);
}

// ---------------------------------------------------------------------------
// f32 -> bf16 cast: x (4 segs of 1M) + qw/kw/vw/ow (1M each) into d_ws.
// ---------------------------------------------------------------------------
__global__ __launch_bounds__(256, 4) void cvt_kernel(
    const float* __restrict__ x,  const float* __restrict__ qw,
    const float* __restrict__ kw, const float* __restrict__ vw,
    const float* __restrict__ ow, unsigned short* __restrict__ dst)
{
  const int seg = blockIdx.y;
  const float* src;
  size_t doff;
  if (seg < 4)       { src = x + (size_t)seg * 1048576; doff = (size_t)seg * 1048576; }
  else if (seg == 4) { src = qw; doff = 4194304u; }
  else if (seg == 5) { src = kw; doff = 4194304u + 1048576u; }
  else if (seg == 6) { src = vw; doff = 4194304u + 2097152u; }
  else               { src = ow; doff = 4194304u + 3145728u; }
  const size_t i = ((size_t)blockIdx.x * 256 + threadIdx.x) * 4;
  float4v v = *(const float4v*)(src + i);
  short4v p;
#pragma unroll
  for (int r = 0; r < 4; ++r) p[r] = (short)f2bf(v[r]);
  *(short4v*)(dst + doff + i) = p;
}

// ---------------------------------------------------------------------------
// GEMM: out = X @ W^T + bias (byte-identical to round 11).
// ---------------------------------------------------------------------------
__global__ __launch_bounds__(256, 2) void gemm_kernel(
    const unsigned short* __restrict__ X,
    const unsigned short* __restrict__ W0, const unsigned short* __restrict__ W1,
    const unsigned short* __restrict__ W2,
    const float* __restrict__ Bi0, const float* __restrict__ Bi1,
    const float* __restrict__ Bi2,
    unsigned short* O0, unsigned short* O1, unsigned short* O2,
    float* OutF, int md0, int md1, int md2)
{
  const int z = blockIdx.z;
  const unsigned short* W  = (z == 0) ? W0  : ((z == 1) ? W1  : W2);
  const float* Bi          = (z == 0) ? Bi0 : ((z == 1) ? Bi1 : Bi2);
  unsigned short* Out      = (z == 0) ? O0  : ((z == 1) ? O1  : O2);
  const int mode           = (z == 0) ? md0 : ((z == 1) ? md1 : md2);

  __shared__ __align__(16) char smem[128 * 32 * 2 * 2];
  __shared__ __align__(16) float tb[32 * 132];   // mode-1 transpose buffer
  char* As = smem;
  char* Bs = smem + 128 * 32 * 2;

  const int t = threadIdx.x, l = t & 63;
  const int w = t >> 6, lr = l & 15, lg = l >> 4;
  const int n0 = blockIdx.x * 128, m0 = blockIdx.y * 128;
  const int wm = (w >> 1) * 64, wn = (w & 1) * 64;

  float4v acc[4][4];
#pragma unroll
  for (int i = 0; i < 4; ++i)
#pragma unroll
    for (int j = 0; j < 4; ++j) acc[i][j] = (float4v){0.f, 0.f, 0.f, 0.f};

  const int c0 = t, c1 = t + 256;
  const int r0 = c0 >> 2, k80 = (c0 & 3) * 8;
  const int r1 = c1 >> 2, k81 = (c1 & 3) * 8;

  for (int k0 = 0; k0 < 1024; k0 += 32) {
    __syncthreads();
    gload_lds16(X + (size_t)(m0 + r0) * 1024 + k0 + k80, As + c0 * 16);
    gload_lds16(X + (size_t)(m0 + r1) * 1024 + k0 + k81, As + c1 * 16);
    gload_lds16(W + (size_t)(n0 + r0) * 1024 + k0 + k80, Bs + c0 * 16);
    gload_lds16(W + (size_t)(n0 + r1) * 1024 + k0 + k81, Bs + c1 * 16);
    __syncthreads();

    short8 af[4], bfr[4];
#pragma unroll
    for (int i = 0; i < 4; ++i)
      af[i] = *(const short8*)(As + (wm + i * 16 + lr) * 64 + lg * 16);
#pragma unroll
    for (int j = 0; j < 4; ++j)
      bfr[j] = *(const short8*)(Bs + (wn + j * 16 + lr) * 64 + lg * 16);
#pragma unroll
    for (int i = 0; i < 4; ++i)
#pragma unroll
      for (int j = 0; j < 4; ++j)
        acc[i][j] = __builtin_amdgcn_mfma_f32_16x16x32_bf16(af[i], bfr[j], acc[i][j], 0, 0, 0);
  }

  float bv[4];
#pragma unroll
  for (int j = 0; j < 4; ++j) bv[j] = Bi[n0 + wn + j * 16 + lr];

  if (mode == 1) {
    const int rbase = (w >> 1) * 16;
    const int row16 = t >> 3, chunk = t & 7;
#pragma unroll
    for (int i = 0; i < 4; ++i) {
#pragma unroll
      for (int j = 0; j < 4; ++j)
#pragma unroll
        for (int r = 0; r < 4; ++r)
          tb[(rbase + lg * 4 + r) * 132 + wn + j * 16 + lr] = acc[i][j][r] + bv[j];
      __syncthreads();
      const int grow = m0 + ((row16 < 16) ? (i * 16 + row16) : (64 + i * 16 + row16 - 16));
      const int b = grow >> 11, sl = grow & 2047;
      const int colg = n0 + chunk * 16;
      const int hh = colg >> 6, d0 = colg & 63;
      float4v v4[4];
#pragma unroll
      for (int q = 0; q < 4; ++q)
        v4[q] = *(const float4v*)(tb + row16 * 132 + chunk * 16 + q * 4);
      uint4v lo, hi;
#pragma unroll
      for (int q = 0; q < 2; ++q) {
        lo[q * 2]     = pkbf(v4[q][0], v4[q][1]);
        lo[q * 2 + 1] = pkbf(v4[q][2], v4[q][3]);
        hi[q * 2]     = pkbf(v4[q + 2][0], v4[q + 2][1]);
        hi[q * 2 + 1] = pkbf(v4[q + 2][2], v4[q + 2][3]);
      }
      unsigned short* dst = Out + ((size_t)(b * H_ + hh) * S_ + sl) * HD_ + d0;
      *(short8*)dst = __builtin_bit_cast(short8, lo);
      *(short8*)(dst + 8) = __builtin_bit_cast(short8, hi);
      __syncthreads();
    }
  } else {
#pragma unroll
    for (int i = 0; i < 4; ++i) {
      const int rowb = m0 + wm + i * 16 + lg * 4;
#pragma unroll
      for (int j = 0; j < 4; ++j) {
        const int col = n0 + wn + j * 16 + lr;
        if (mode == 2) {
          const int b = rowb >> 11, s = rowb & 2047;
          const int hh = col >> 6, d = col & 63;
          uint2v pk2;
          pk2[0] = pkbf(acc[i][j][0] + bv[j], acc[i][j][1] + bv[j]);
          pk2[1] = pkbf(acc[i][j][2] + bv[j], acc[i][j][3] + bv[j]);
          *(short4v*)(Out + ((size_t)(b * H_ + hh) * HD_ + d) * S_ + s) =
              __builtin_bit_cast(short4v, pk2);
        } else {
#pragma unroll
          for (int r = 0; r < 4; ++r)
            OutF[(size_t)(rowb + r) * 1024 + col] = acc[i][j][r] + bv[j];
        }
      }
    }
  }
}

// ---------------------------------------------------------------------------
// Flash attention v4 (round-11 verified); ONLY change: the O^T un-transpose
// buffer now ALIASES the dead K-dbuf region after the loop's final barrier
// (no prefetch on last iter; barrier drains all LDS reads) -> LDS 50688 ->
// 32768, residency 2 -> up to 5 blocks/CU for this latency-bound kernel.
// ---------------------------------------------------------------------------
__global__ __launch_bounds__(256, 2) void attn_kernel(
    const unsigned short* __restrict__ Q, const unsigned short* __restrict__ K,
    const unsigned short* __restrict__ VT, unsigned short* __restrict__ O)
{
  // K dbuf 2x8KB + V dbuf 2x8KB; epilogue transpose buffer aliases [0,17664)
  __shared__ __align__(16) char smem[32768];

  const int t = threadIdx.x, l = t & 63;
  const int w = t >> 6, lr = l & 15, lg = l >> 4;
  const int bh = blockIdx.x;
  const int it = 31 - (int)blockIdx.y;   // LPT: heavy tiles first
  const int h = bh & 15;

  const unsigned short* qbp = Q + (size_t)bh * S_ * HD_;
  const unsigned short* kbp = K + (size_t)bh * S_ * HD_;
  const unsigned short* vbp = VT + (size_t)bh * HD_ * S_;

  const float slope2 = __builtin_amdgcn_exp2f(-0.5f * (float)(h + 1)) * LOG2E;
  const float qksc = 0.125f * LOG2E;

  // staging chunk mapping (XOR swizzle) -- identical to round 11
  const int g0 = t, g1 = t + 256;
  const int sr0 = g0 >> 3, sc0 = (g0 & 7) ^ (sr0 & 7);
  const int sr1 = g1 >> 3, sc1 = (g1 & 7) ^ (sr1 & 7);

  const int fchunk = ((4 + lg) ^ (lr & 7)) * 16;   // ks=1
  const int fchunk0 = ((lg) ^ (lr & 7)) * 16;      // ks=0

  const int qrow = it * 64 + w * 16;
  const int qpos = qrow + lr;

  float kb16[4][4];
#pragma unroll
  for (int nj = 0; nj < 4; ++nj)
#pragma unroll
    for (int r = 0; r < 4; ++r)
      kb16[nj][r] = slope2 * (float)(nj * 16 + lg * 4 + r);

  short8 qf[2];
#pragma unroll
  for (int ks = 0; ks < 2; ++ks)
    qf[ks] = *(const short8*)(qbp + (size_t)(qrow + lr) * HD_ + ks * 32 + lg * 8);

  float4v o_acc[4];
#pragma unroll
  for (int dt = 0; dt < 4; ++dt) o_acc[dt] = (float4v){0.f, 0.f, 0.f, 0.f};
  float m_st = -1e30f, l_st = 0.f;

  // prefetch j=0 into buffer 0
  gload_lds16(kbp + (size_t)sr0 * HD_ + sc0 * 8, smem + g0 * 16);
  gload_lds16(kbp + (size_t)sr1 * HD_ + sc1 * 8, smem + g1 * 16);
  gload_lds16(vbp + (size_t)sr0 * S_ + sc0 * 8, smem + 16384 + g0 * 16);
  gload_lds16(vbp + (size_t)sr1 * S_ + sc1 * 8, smem + 16384 + g1 * 16);
  __syncthreads();

  for (int j = 0; j <= it; ++j) {
    const int cur = j & 1;
    char* Ks = smem + (cur ? 8192 : 0);
    char* Vs = smem + 16384 + (cur ? 8192 : 0);
    if (j < it) {
      char* Kn = smem + (cur ? 0 : 8192);
      char* Vn = smem + 16384 + (cur ? 0 : 8192);
      const int jn = j + 1;
      gload_lds16(kbp + (size_t)(jn * 64 + sr0) * HD_ + sc0 * 8, Kn + g0 * 16);
      gload_lds16(kbp + (size_t)(jn * 64 + sr1) * HD_ + sc1 * 8, Kn + g1 * 16);
      gload_lds16(vbp + (size_t)sr0 * S_ + jn * 64 + sc0 * 8, Vn + g0 * 16);
      gload_lds16(vbp + (size_t)sr1 * S_ + jn * 64 + sc1 * 8, Vn + g1 * 16);
    }

    // S^T = K Q^T
    float4v s_acc[4];
#pragma unroll
    for (int nj = 0; nj < 4; ++nj) {
      s_acc[nj] = (float4v){0.f, 0.f, 0.f, 0.f};
      short8 kf0 = *(const short8*)(Ks + (nj * 16 + lr) * 128 + fchunk0);
      s_acc[nj] = __builtin_amdgcn_mfma_f32_16x16x32_bf16(kf0, qf[0], s_acc[nj], 0, 0, 0);
      short8 kf1 = *(const short8*)(Ks + (nj * 16 + lr) * 128 + fchunk);
      s_acc[nj] = __builtin_amdgcn_mfma_f32_16x16x32_bf16(kf1, qf[1], s_acc[nj], 0, 0, 0);
    }

    const float cj = slope2 * (float)(j * 64);
#pragma unroll
    for (int nj = 0; nj < 4; ++nj)
#pragma unroll
      for (int r = 0; r < 4; ++r)
        s_acc[nj][r] = s_acc[nj][r] * qksc + (cj + kb16[nj][r]);
    if (j == it) {
#pragma unroll
      for (int nj = 0; nj < 4; ++nj)
#pragma unroll
        for (int r = 0; r < 4; ++r) {
          const int kpos = j * 64 + nj * 16 + lg * 4 + r;
          if (kpos > qpos) s_acc[nj][r] = -1e30f;
        }
    }

    // online softmax: in-lane reduce over 16 + 2 cross-quad shuffles
    float mx = s_acc[0][0];
#pragma unroll
    for (int nj = 0; nj < 4; ++nj)
#pragma unroll
      for (int r = 0; r < 4; ++r) mx = fmaxf(mx, s_acc[nj][r]);
    mx = fmaxf(mx, __shfl_xor(mx, 16, 64));
    mx = fmaxf(mx, __shfl_xor(mx, 32, 64));
    const float mn = fmaxf(m_st, mx);
    const float alpha = __builtin_amdgcn_exp2f(m_st - mn);
    m_st = mn;
    float rsum = 0.f;
#pragma unroll
    for (int nj = 0; nj < 4; ++nj)
#pragma unroll
      for (int r = 0; r < 4; ++r) {
        const float p = __builtin_amdgcn_exp2f(s_acc[nj][r] - mn);
        s_acc[nj][r] = p;
        rsum += p;
      }
    rsum += __shfl_xor(rsum, 16, 64);
    rsum += __shfl_xor(rsum, 32, 64);
    l_st = alpha * l_st + rsum;
#pragma unroll
    for (int dt = 0; dt < 4; ++dt)
#pragma unroll
      for (int r = 0; r < 4; ++r) o_acc[dt][r] *= alpha;

    // P^T -> bf16 K=32 B-fragments via packed cvt
    short8 pT[2];
#pragma unroll
    for (int njp = 0; njp < 2; ++njp) {
      uint4v u;
      u[0] = pkbf(s_acc[njp * 2][0], s_acc[njp * 2][1]);
      u[1] = pkbf(s_acc[njp * 2][2], s_acc[njp * 2][3]);
      u[2] = pkbf(s_acc[njp * 2 + 1][0], s_acc[njp * 2 + 1][1]);
      u[3] = pkbf(s_acc[njp * 2 + 1][2], s_acc[njp * 2 + 1][3]);
      pT[njp] = __builtin_bit_cast(short8, u);
    }

    // O^T += V^T P^T
    const int vcl = lr & 7;
#pragma unroll
    for (int dt = 0; dt < 4; ++dt) {
      const char* rowp = Vs + (dt * 16 + lr) * 128;
#pragma unroll
      for (int njp = 0; njp < 2; ++njp) {
        const int cA = ((njp * 4 + (lg >> 1)) ^ vcl) * 16 + (lg & 1) * 8;
        const int cB = ((njp * 4 + 2 + (lg >> 1)) ^ vcl) * 16 + (lg & 1) * 8;
        short4v v0 = *(const short4v*)(rowp + cA);
        short4v v1 = *(const short4v*)(rowp + cB);
        short8 vf8;
#pragma unroll
        for (int e = 0; e < 4; ++e) { vf8[e] = v0[e]; vf8[e + 4] = v1[e]; }
        o_acc[dt] = __builtin_amdgcn_mfma_f32_16x16x32_bf16(vf8, pT[njp], o_acc[dt], 0, 0, 0);
      }
    }
    __syncthreads();
  }

  // epilogue: un-transpose O^T via wave-private LDS (ALIASES dead K dbuf
  // region -- safe: last iter issues no prefetch, final barrier drained all
  // LDS reads). Layout per wave: [64 d][17 f32] + 16 f32 l at offset 4352.
  char* tw = smem + w * 4416;
#pragma unroll
  for (int dt = 0; dt < 4; ++dt)
#pragma unroll
    for (int r = 0; r < 4; ++r)
      *(float*)(tw + ((dt * 16 + lg * 4 + r) * 17 + lr) * 4) = o_acc[dt][r];
  if (lg == 0) *(float*)(tw + 4352 + lr * 4) = l_st;

  const int q2 = l >> 2, dbase = (l & 3) * 16;
  const float invl = 1.0f / *(const float*)(tw + 4352 + q2 * 4);
  uint4v os0, os1;
#pragma unroll
  for (int k = 0; k < 8; ++k) {
    const float va = *(const float*)(tw + ((dbase + 2 * k) * 17 + q2) * 4) * invl;
    const float vb = *(const float*)(tw + ((dbase + 2 * k + 1) * 17 + q2) * 4) * invl;
    if (k < 4) os0[k] = pkbf(va, vb); else os1[k - 4] = pkbf(va, vb);
  }
  const int brow = (bh >> 4) * S_;
  unsigned short* op = O + (size_t)(brow + qrow + q2) * 1024 + h * 64 + dbase;
  *(short8*)op = __builtin_bit_cast(short8, os0);
  *(short8*)(op + 8) = __builtin_bit_cast(short8, os1);
}

extern "C" void kernel_launch(void* const* d_in, const int* in_sizes, int n_in,
                              void* d_out, int out_size, void* d_ws, size_t ws_size,
                              hipStream_t stream) {
  (void)in_sizes; (void)n_in; (void)out_size; (void)ws_size;
  const float* x  = (const float*)d_in[0];
  const float* qw = (const float*)d_in[1];
  const float* qb = (const float*)d_in[2];
  const float* kw = (const float*)d_in[3];
  const float* kb = (const float*)d_in[4];
  const float* vw = (const float*)d_in[5];
  const float* vb = (const float*)d_in[6];
  const float* ow = (const float*)d_in[7];
  const float* ob = (const float*)d_in[8];
  float* out = (float*)d_out;

  unsigned short* xb  = (unsigned short*)d_ws;              // [4096,1024] bf16
  unsigned short* qwb = xb  + (size_t)M_ * D_;
  unsigned short* kwb = qwb + (size_t)D_ * D_;
  unsigned short* vwb = kwb + (size_t)D_ * D_;
  unsigned short* owb = vwb + (size_t)D_ * D_;
  unsigned short* qws = owb + (size_t)D_ * D_;              // [B,H,S,hd]
  unsigned short* kws = qws + (size_t)M_ * D_;              // [B,H,S,hd]
  unsigned short* vws = kws + (size_t)M_ * D_;              // [B,H,hd,S]
  unsigned short* aws = vws + (size_t)M_ * D_;              // [B*S, H*hd]

  cvt_kernel<<<dim3(1024, 8), dim3(256), 0, stream>>>(x, qw, kw, vw, ow, xb);
  gemm_kernel<<<dim3(8, 32, 3), dim3(256), 0, stream>>>(
      xb, qwb, kwb, vwb, qb, kb, vb, qws, kws, vws, out, 1, 1, 2);
  attn_kernel<<<dim3(32, 32), dim3(256), 0, stream>>>(qws, kws, vws, aws);
  gemm_kernel<<<dim3(8, 32, 1), dim3(256), 0, stream>>>(
      aws, owb, owb, owb, ob, ob, ob, aws, aws, aws, out, 0, 0, 0);
}

// Round 13
// 186.425 us; speedup vs baseline: 1.0547x; 1.0428x over previous
//
#include <hip/hip_runtime.h>
#include <hip/hip_bf16.h>

typedef __attribute__((ext_vector_type(8))) short short8;
typedef __attribute__((ext_vector_type(4))) float float4v;
typedef __attribute__((ext_vector_type(4))) short short4v;
typedef __attribute__((ext_vector_type(4))) unsigned int uint4v;
typedef __attribute__((ext_vector_type(2))) unsigned int uint2v;

#define B_ 2
#define S_ 2048
#define D_ 1024
#define H_ 16
#define HD_ 64
#define M_ 4096
#define LOG2E 1.442695040888963f

__device__ __forceinline__ unsigned short f2bf(float f) {
  unsigned int u = __builtin_bit_cast(unsigned int, f);
  u += 0x7fffu + ((u >> 16) & 1u);   // RNE (finite values only)
  return (unsigned short)(u >> 16);
}

// packed f32x2 -> bf16x2 (RNE), one v_cvt_pk_bf16_f32
__device__ __forceinline__ unsigned int pkbf(float a, float b) {
  __hip_bfloat162 h = __float22bfloat162_rn(make_float2(a, b));
  unsigned int u;
  __builtin_memcpy(&u, &h, sizeof(u));
  return u;
}

__device__ __forceinline__ void gload_lds16(const void* g, void* l) {
  __builtin_amdgcn_global_load_lds(
      (const __attribute__((address_space(1))) void*)g,
      (__attribute__((address_space(3))) void*)l, 16, 0, 0);
}

// ---------------------------------------------------------------------------
// f32 -> bf16 cast (byte-identical to round 12).
// ---------------------------------------------------------------------------
__global__ __launch_bounds__(256, 4) void cvt_kernel(
    const float* __restrict__ x,  const float* __restrict__ qw,
    const float* __restrict__ kw, const float* __restrict__ vw,
    const float* __restrict__ ow, unsigned short* __restrict__ dst)
{
  const int seg = blockIdx.y;
  const float* src;
  size_t doff;
  if (seg < 4)       { src = x + (size_t)seg * 1048576; doff = (size_t)seg * 1048576; }
  else if (seg == 4) { src = qw; doff = 4194304u; }
  else if (seg == 5) { src = kw; doff = 4194304u + 1048576u; }
  else if (seg == 6) { src = vw; doff = 4194304u + 2097152u; }
  else               { src = ow; doff = 4194304u + 3145728u; }
  const size_t i = ((size_t)blockIdx.x * 256 + threadIdx.x) * 4;
  float4v v = *(const float4v*)(src + i);
  short4v p;
#pragma unroll
  for (int r = 0; r < 4; ++r) p[r] = (short)f2bf(v[r]);
  *(short4v*)(dst + doff + i) = p;
}

// ---------------------------------------------------------------------------
// GEMM: out = X @ W^T + bias.  Templated on TN (N-tile width).
// TN=128: QKV (modes 1/2, K-loop byte-identical to round 12).
// TN=64:  O-projection mode 0 only -> grid 512 blocks = 2/CU (was 1/CU).
// ---------------------------------------------------------------------------
template <int TN>
__global__ __launch_bounds__(256, 2) void gemm_kernel(
    const unsigned short* __restrict__ X,
    const unsigned short* __restrict__ W0, const unsigned short* __restrict__ W1,
    const unsigned short* __restrict__ W2,
    const float* __restrict__ Bi0, const float* __restrict__ Bi1,
    const float* __restrict__ Bi2,
    unsigned short* O0, unsigned short* O1, unsigned short* O2,
    float* OutF, int md0, int md1, int md2)
{
  constexpr int NJ = TN / 32;     // 16-col acc tiles per wave
  const int z = blockIdx.z;
  const unsigned short* W  = (z == 0) ? W0  : ((z == 1) ? W1  : W2);
  const float* Bi          = (z == 0) ? Bi0 : ((z == 1) ? Bi1 : Bi2);
  unsigned short* Out      = (z == 0) ? O0  : ((z == 1) ? O1  : O2);
  const int mode           = (z == 0) ? md0 : ((z == 1) ? md1 : md2);

  __shared__ __align__(16) char smem[8192 + TN * 64];
  __shared__ __align__(16) float tb[32 * 132];   // mode-1 transpose buffer
  char* As = smem;
  char* Bs = smem + 8192;

  const int t = threadIdx.x, l = t & 63;
  const int w = t >> 6, lr = l & 15, lg = l >> 4;
  const int n0 = blockIdx.x * TN, m0 = blockIdx.y * 128;
  const int wm = (w >> 1) * 64, wn = (w & 1) * (TN / 2);

  float4v acc[4][NJ];
#pragma unroll
  for (int i = 0; i < 4; ++i)
#pragma unroll
    for (int j = 0; j < NJ; ++j) acc[i][j] = (float4v){0.f, 0.f, 0.f, 0.f};

  const int c0 = t, c1 = t + 256;
  const int r0 = c0 >> 2, k80 = (c0 & 3) * 8;
  const int r1 = c1 >> 2, k81 = (c1 & 3) * 8;

  for (int k0 = 0; k0 < 1024; k0 += 32) {
    __syncthreads();
    gload_lds16(X + (size_t)(m0 + r0) * 1024 + k0 + k80, As + c0 * 16);
    gload_lds16(X + (size_t)(m0 + r1) * 1024 + k0 + k81, As + c1 * 16);
    gload_lds16(W + (size_t)(n0 + r0) * 1024 + k0 + k80, Bs + c0 * 16);
    if (TN == 128)
      gload_lds16(W + (size_t)(n0 + r1) * 1024 + k0 + k81, Bs + c1 * 16);
    __syncthreads();

    short8 af[4], bfr[NJ];
#pragma unroll
    for (int i = 0; i < 4; ++i)
      af[i] = *(const short8*)(As + (wm + i * 16 + lr) * 64 + lg * 16);
#pragma unroll
    for (int j = 0; j < NJ; ++j)
      bfr[j] = *(const short8*)(Bs + (wn + j * 16 + lr) * 64 + lg * 16);
#pragma unroll
    for (int i = 0; i < 4; ++i)
#pragma unroll
      for (int j = 0; j < NJ; ++j)
        acc[i][j] = __builtin_amdgcn_mfma_f32_16x16x32_bf16(af[i], bfr[j], acc[i][j], 0, 0, 0);
  }

  float bv[NJ];
#pragma unroll
  for (int j = 0; j < NJ; ++j) bv[j] = Bi[n0 + wn + j * 16 + lr];

  if constexpr (TN == 128) {
    if (mode == 1) {
      const int rbase = (w >> 1) * 16;
      const int row16 = t >> 3, chunk = t & 7;
#pragma unroll
      for (int i = 0; i < 4; ++i) {
#pragma unroll
        for (int j = 0; j < 4; ++j)
#pragma unroll
          for (int r = 0; r < 4; ++r)
            tb[(rbase + lg * 4 + r) * 132 + wn + j * 16 + lr] = acc[i][j][r] + bv[j];
        __syncthreads();
        const int grow = m0 + ((row16 < 16) ? (i * 16 + row16) : (64 + i * 16 + row16 - 16));
        const int b = grow >> 11, sl = grow & 2047;
        const int colg = n0 + chunk * 16;
        const int hh = colg >> 6, d0 = colg & 63;
        float4v v4[4];
#pragma unroll
        for (int q = 0; q < 4; ++q)
          v4[q] = *(const float4v*)(tb + row16 * 132 + chunk * 16 + q * 4);
        uint4v lo, hi;
#pragma unroll
        for (int q = 0; q < 2; ++q) {
          lo[q * 2]     = pkbf(v4[q][0], v4[q][1]);
          lo[q * 2 + 1] = pkbf(v4[q][2], v4[q][3]);
          hi[q * 2]     = pkbf(v4[q + 2][0], v4[q + 2][1]);
          hi[q * 2 + 1] = pkbf(v4[q + 2][2], v4[q + 2][3]);
        }
        unsigned short* dst = Out + ((size_t)(b * H_ + hh) * S_ + sl) * HD_ + d0;
        *(short8*)dst = __builtin_bit_cast(short8, lo);
        *(short8*)(dst + 8) = __builtin_bit_cast(short8, hi);
        __syncthreads();
      }
      return;
    }
    if (mode == 2) {
#pragma unroll
      for (int i = 0; i < 4; ++i) {
        const int rowb = m0 + wm + i * 16 + lg * 4;
#pragma unroll
        for (int j = 0; j < 4; ++j) {
          const int col = n0 + wn + j * 16 + lr;
          const int b = rowb >> 11, s = rowb & 2047;
          const int hh = col >> 6, d = col & 63;
          uint2v pk2;
          pk2[0] = pkbf(acc[i][j][0] + bv[j], acc[i][j][1] + bv[j]);
          pk2[1] = pkbf(acc[i][j][2] + bv[j], acc[i][j][3] + bv[j]);
          *(short4v*)(Out + ((size_t)(b * H_ + hh) * HD_ + d) * S_ + s) =
              __builtin_bit_cast(short4v, pk2);
        }
      }
      return;
    }
  }
  // mode 0: f32 out
#pragma unroll
  for (int i = 0; i < 4; ++i) {
    const int rowb = m0 + wm + i * 16 + lg * 4;
#pragma unroll
    for (int j = 0; j < NJ; ++j) {
      const int col = n0 + wn + j * 16 + lr;
#pragma unroll
      for (int r = 0; r < 4; ++r)
        OutF[(size_t)(rowb + r) * 1024 + col] = acc[i][j][r] + bv[j];
    }
  }
}

// ---------------------------------------------------------------------------
// Flash attention v5: round-12 structure with two serial-chain cuts:
//  - l accumulated via ones-A MFMA alongside O^T (deletes the 15-add sum
//    tree + 2 cross-quad shuffles from every iteration; alpha-rescaled
//    exactly like o_acc, so softmax math is unchanged -- r3-verified idea)
//  - kb16[16] register array replaced by inline bias arithmetic (-12 VGPR)
// ---------------------------------------------------------------------------
__global__ __launch_bounds__(256, 2) void attn_kernel(
    const unsigned short* __restrict__ Q, const unsigned short* __restrict__ K,
    const unsigned short* __restrict__ VT, unsigned short* __restrict__ O)
{
  // K dbuf 2x8KB + V dbuf 2x8KB; epilogue transpose buffer aliases [0,17664)
  __shared__ __align__(16) char smem[32768];

  const int t = threadIdx.x, l = t & 63;
  const int w = t >> 6, lr = l & 15, lg = l >> 4;
  const int bh = blockIdx.x;
  const int it = 31 - (int)blockIdx.y;   // LPT: heavy tiles first
  const int h = bh & 15;

  const unsigned short* qbp = Q + (size_t)bh * S_ * HD_;
  const unsigned short* kbp = K + (size_t)bh * S_ * HD_;
  const unsigned short* vbp = VT + (size_t)bh * HD_ * S_;

  const float slope2 = __builtin_amdgcn_exp2f(-0.5f * (float)(h + 1)) * LOG2E;
  const float qksc = 0.125f * LOG2E;

  const int g0 = t, g1 = t + 256;
  const int sr0 = g0 >> 3, sc0 = (g0 & 7) ^ (sr0 & 7);
  const int sr1 = g1 >> 3, sc1 = (g1 & 7) ^ (sr1 & 7);

  const int fchunk = ((4 + lg) ^ (lr & 7)) * 16;   // ks=1
  const int fchunk0 = ((lg) ^ (lr & 7)) * 16;      // ks=0

  const int qrow = it * 64 + w * 16;
  const int qpos = qrow + lr;

  short8 ones;
#pragma unroll
  for (int e = 0; e < 8; ++e) ones[e] = (short)0x3F80;  // bf16 1.0

  short8 qf[2];
#pragma unroll
  for (int ks = 0; ks < 2; ++ks)
    qf[ks] = *(const short8*)(qbp + (size_t)(qrow + lr) * HD_ + ks * 32 + lg * 8);

  float4v o_acc[4], l_acc;
#pragma unroll
  for (int dt = 0; dt < 4; ++dt) o_acc[dt] = (float4v){0.f, 0.f, 0.f, 0.f};
  l_acc = (float4v){0.f, 0.f, 0.f, 0.f};
  float m_st = -1e30f;

  // prefetch j=0 into buffer 0
  gload_lds16(kbp + (size_t)sr0 * HD_ + sc0 * 8, smem + g0 * 16);
  gload_lds16(kbp + (size_t)sr1 * HD_ + sc1 * 8, smem + g1 * 16);
  gload_lds16(vbp + (size_t)sr0 * S_ + sc0 * 8, smem + 16384 + g0 * 16);
  gload_lds16(vbp + (size_t)sr1 * S_ + sc1 * 8, smem + 16384 + g1 * 16);
  __syncthreads();

  for (int j = 0; j <= it; ++j) {
    const int cur = j & 1;
    char* Ks = smem + (cur ? 8192 : 0);
    char* Vs = smem + 16384 + (cur ? 8192 : 0);
    if (j < it) {
      char* Kn = smem + (cur ? 0 : 8192);
      char* Vn = smem + 16384 + (cur ? 0 : 8192);
      const int jn = j + 1;
      gload_lds16(kbp + (size_t)(jn * 64 + sr0) * HD_ + sc0 * 8, Kn + g0 * 16);
      gload_lds16(kbp + (size_t)(jn * 64 + sr1) * HD_ + sc1 * 8, Kn + g1 * 16);
      gload_lds16(vbp + (size_t)sr0 * S_ + jn * 64 + sc0 * 8, Vn + g0 * 16);
      gload_lds16(vbp + (size_t)sr1 * S_ + jn * 64 + sc1 * 8, Vn + g1 * 16);
    }

    // S^T = K Q^T
    float4v s_acc[4];
#pragma unroll
    for (int nj = 0; nj < 4; ++nj) {
      s_acc[nj] = (float4v){0.f, 0.f, 0.f, 0.f};
      short8 kf0 = *(const short8*)(Ks + (nj * 16 + lr) * 128 + fchunk0);
      s_acc[nj] = __builtin_amdgcn_mfma_f32_16x16x32_bf16(kf0, qf[0], s_acc[nj], 0, 0, 0);
      short8 kf1 = *(const short8*)(Ks + (nj * 16 + lr) * 128 + fchunk);
      s_acc[nj] = __builtin_amdgcn_mfma_f32_16x16x32_bf16(kf1, qf[1], s_acc[nj], 0, 0, 0);
    }

    // scale + ALiBi bias (inline; compiler hoists slope2*r)
#pragma unroll
    for (int nj = 0; nj < 4; ++nj) {
      const float cb = slope2 * (float)(j * 64 + nj * 16 + lg * 4);
#pragma unroll
      for (int r = 0; r < 4; ++r)
        s_acc[nj][r] = s_acc[nj][r] * qksc + (cb + slope2 * (float)r);
    }
    if (j == it) {
#pragma unroll
      for (int nj = 0; nj < 4; ++nj)
#pragma unroll
        for (int r = 0; r < 4; ++r) {
          const int kpos = j * 64 + nj * 16 + lg * 4 + r;
          if (kpos > qpos) s_acc[nj][r] = -1e30f;
        }
    }

    // online softmax: in-lane max + 2 cross-quad shuffles; sum via ones-MFMA
    float mx = s_acc[0][0];
#pragma unroll
    for (int nj = 0; nj < 4; ++nj)
#pragma unroll
      for (int r = 0; r < 4; ++r) mx = fmaxf(mx, s_acc[nj][r]);
    mx = fmaxf(mx, __shfl_xor(mx, 16, 64));
    mx = fmaxf(mx, __shfl_xor(mx, 32, 64));
    const float mn = fmaxf(m_st, mx);
    const float alpha = __builtin_amdgcn_exp2f(m_st - mn);
    m_st = mn;
#pragma unroll
    for (int nj = 0; nj < 4; ++nj)
#pragma unroll
      for (int r = 0; r < 4; ++r)
        s_acc[nj][r] = __builtin_amdgcn_exp2f(s_acc[nj][r] - mn);
#pragma unroll
    for (int dt = 0; dt < 4; ++dt)
#pragma unroll
      for (int r = 0; r < 4; ++r) o_acc[dt][r] *= alpha;
#pragma unroll
    for (int r = 0; r < 4; ++r) l_acc[r] *= alpha;

    // P^T -> bf16 K=32 B-fragments via packed cvt
    short8 pT[2];
#pragma unroll
    for (int njp = 0; njp < 2; ++njp) {
      uint4v u;
      u[0] = pkbf(s_acc[njp * 2][0], s_acc[njp * 2][1]);
      u[1] = pkbf(s_acc[njp * 2][2], s_acc[njp * 2][3]);
      u[2] = pkbf(s_acc[njp * 2 + 1][0], s_acc[njp * 2 + 1][1]);
      u[3] = pkbf(s_acc[njp * 2 + 1][2], s_acc[njp * 2 + 1][3]);
      pT[njp] = __builtin_bit_cast(short8, u);
    }

    // l += rowsum(P) via ones-A MFMA (off the critical path, runs with PV)
    l_acc = __builtin_amdgcn_mfma_f32_16x16x32_bf16(ones, pT[0], l_acc, 0, 0, 0);
    l_acc = __builtin_amdgcn_mfma_f32_16x16x32_bf16(ones, pT[1], l_acc, 0, 0, 0);

    // O^T += V^T P^T
    const int vcl = lr & 7;
#pragma unroll
    for (int dt = 0; dt < 4; ++dt) {
      const char* rowp = Vs + (dt * 16 + lr) * 128;
#pragma unroll
      for (int njp = 0; njp < 2; ++njp) {
        const int cA = ((njp * 4 + (lg >> 1)) ^ vcl) * 16 + (lg & 1) * 8;
        const int cB = ((njp * 4 + 2 + (lg >> 1)) ^ vcl) * 16 + (lg & 1) * 8;
        short4v v0 = *(const short4v*)(rowp + cA);
        short4v v1 = *(const short4v*)(rowp + cB);
        short8 vf8;
#pragma unroll
        for (int e = 0; e < 4; ++e) { vf8[e] = v0[e]; vf8[e + 4] = v1[e]; }
        o_acc[dt] = __builtin_amdgcn_mfma_f32_16x16x32_bf16(vf8, pT[njp], o_acc[dt], 0, 0, 0);
      }
    }
    __syncthreads();
  }

  // epilogue: un-transpose O^T via wave-private LDS (aliases dead K dbuf)
  char* tw = smem + w * 4416;
#pragma unroll
  for (int dt = 0; dt < 4; ++dt)
#pragma unroll
    for (int r = 0; r < 4; ++r)
      *(float*)(tw + ((dt * 16 + lg * 4 + r) * 17 + lr) * 4) = o_acc[dt][r];
  if (lg == 0) *(float*)(tw + 4352 + lr * 4) = l_acc[0];

  const int q2 = l >> 2, dbase = (l & 3) * 16;
  const float invl = 1.0f / *(const float*)(tw + 4352 + q2 * 4);
  uint4v os0, os1;
#pragma unroll
  for (int k = 0; k < 8; ++k) {
    const float va = *(const float*)(tw + ((dbase + 2 * k) * 17 + q2) * 4) * invl;
    const float vb = *(const float*)(tw + ((dbase + 2 * k + 1) * 17 + q2) * 4) * invl;
    if (k < 4) os0[k] = pkbf(va, vb); else os1[k - 4] = pkbf(va, vb);
  }
  const int brow = (bh >> 4) * S_;
  unsigned short* op = O + (size_t)(brow + qrow + q2) * 1024 + h * 64 + dbase;
  *(short8*)op = __builtin_bit_cast(short8, os0);
  *(short8*)(op + 8) = __builtin_bit_cast(short8, os1);
}

extern "C" void kernel_launch(void* const* d_in, const int* in_sizes, int n_in,
                              void* d_out, int out_size, void* d_ws, size_t ws_size,
                              hipStream_t stream) {
  (void)in_sizes; (void)n_in; (void)out_size; (void)ws_size;
  const float* x  = (const float*)d_in[0];
  const float* qw = (const float*)d_in[1];
  const float* qb = (const float*)d_in[2];
  const float* kw = (const float*)d_in[3];
  const float* kb = (const float*)d_in[4];
  const float* vw = (const float*)d_in[5];
  const float* vb = (const float*)d_in[6];
  const float* ow = (const float*)d_in[7];
  const float* ob = (const float*)d_in[8];
  float* out = (float*)d_out;

  unsigned short* xb  = (unsigned short*)d_ws;              // [4096,1024] bf16
  unsigned short* qwb = xb  + (size_t)M_ * D_;
  unsigned short* kwb = qwb + (size_t)D_ * D_;
  unsigned short* vwb = kwb + (size_t)D_ * D_;
  unsigned short* owb = vwb + (size_t)D_ * D_;
  unsigned short* qws = owb + (size_t)D_ * D_;              // [B,H,S,hd]
  unsigned short* kws = qws + (size_t)M_ * D_;              // [B,H,S,hd]
  unsigned short* vws = kws + (size_t)M_ * D_;              // [B,H,hd,S]
  unsigned short* aws = vws + (size_t)M_ * D_;              // [B*S, H*hd]

  cvt_kernel<<<dim3(1024, 8), dim3(256), 0, stream>>>(x, qw, kw, vw, ow, xb);
  gemm_kernel<128><<<dim3(8, 32, 3), dim3(256), 0, stream>>>(
      xb, qwb, kwb, vwb, qb, kb, vb, qws, kws, vws, out, 1, 1, 2);
  attn_kernel<<<dim3(32, 32), dim3(256), 0, stream>>>(qws, kws, vws, aws);
  gemm_kernel<64><<<dim3(16, 32, 1), dim3(256), 0, stream>>>(
      aws, owb, owb, owb, ob, ob, ob, aws, aws, aws, out, 0, 0, 0);
}